// Round 10
// baseline (3124.772 us; speedup 1.0000x reference)
//
#include <hip/hip_runtime.h>
#include <stdint.h>

typedef __attribute__((ext_vector_type(4))) int i32x4;

static constexpr int BB = 256, TT = 64, NIN = 700, NKP = 768, HH = 2048, OO = 20;
static constexpr float THRESH_V = 0.3f;
static constexpr int NBLK = 256;                 // persistent: 4 m-tiles (M64) x 64 n-tiles (N32)
static constexpr int NREC = 16;                  // rec K-chunks (128B)
static constexpr int XNIT = 11;                  // xproj K-chunks (64B): 704 covers NIN=700; rest is zero-pad (exact skip)

// ---------------- ws layout (bytes) ----------------
static constexpr size_t OFF_HMEM  = 0;           // 256*2048*4
static constexpr size_t OFF_SPK0  = 2097152;     // 256*2048*1 (i8)
static constexpr size_t OFF_OMEM  = 2621440;
static constexpr size_t OFF_OSPK  = 2641920;
static constexpr size_t OFF_OSUM  = 2662400;
static constexpr size_t OFF_BAR   = 2682880;     // grid-barrier cnt @+0, flag @+128
static constexpr size_t ZERO_END  = 2683904;     // memset [0, ZERO_END) every launch (graph-replay safe)
static constexpr size_t OFF_SPK1  = 2683904;     // 524288
static constexpr size_t OFF_ALPHA = 3208192;     // 256
static constexpr size_t OFF_WHHD  = 3208448;     // 4 planes x 2048*2048 i8
static constexpr size_t WHH_PLANE = 4194304;
static constexpr size_t OFF_WIHD  = 19985664;    // 4 planes x 2048*768 i8
static constexpr size_t WIH_PLANE = 1572864;
static constexpr size_t OFF_XD    = 26277120;    // 4 planes x 64*256*768 i8
static constexpr size_t XD_PLANE  = 12582912;
static constexpr size_t OFF_XP    = 76608768;    // f32 [64][256][2048] = 128 MiB
static constexpr size_t WS_NEED   = 210826496;   // ~201 MiB (ws = 256 MiB per poison-fill evidence)

// ---------------- sync primitives ----------------
#define WAIT_VM12() asm volatile("s_waitcnt vmcnt(12)" ::: "memory")
#define WAIT_VM6()  asm volatile("s_waitcnt vmcnt(6)" ::: "memory")
#define WAIT_VM0()  asm volatile("s_waitcnt vmcnt(0)" ::: "memory")
#define SCHED0()    __builtin_amdgcn_sched_barrier(0)

// ---------------- digit helpers (identical to validated round 5) ----------------
__device__ __forceinline__ void wdig(float w, double scale, signed char d[4]) {
    int q = (int)rint((double)w * scale);
    int t0 = (int)(signed char)(q & 0xFF); q = (q - t0) >> 8;
    int t1 = (int)(signed char)(q & 0xFF); q = (q - t1) >> 8;
    int t2 = (int)(signed char)(q & 0xFF); q = (q - t2) >> 8;
    d[0] = (signed char)t0; d[1] = (signed char)t1;
    d[2] = (signed char)t2; d[3] = (signed char)q;
}

// ---------------- LDS fragment reads (validated) ----------------
__device__ __forceinline__ i32x4 ld_rec(const uint8_t* base, int row, int sl) {
    return *reinterpret_cast<const i32x4*>(base + row * 128 + ((sl ^ (row & 7)) << 4));
}
__device__ __forceinline__ i32x4 ld_x(const uint8_t* base, int row, int s) {
    int phys = (s + (row >> 1)) & 3;
    return *reinterpret_cast<const i32x4*>(base + row * 64 + (phys << 4));
}

__device__ __forceinline__ void gload(const uint8_t* src, uint8_t* dst) {
    __builtin_amdgcn_global_load_lds((const __attribute__((address_space(1))) void*)src,
                                     (__attribute__((address_space(3))) void*)dst, 16, 0, 0);
}

// ---------------- stage one 24KB chunk (6 gload_lds per wave, uniform; validated) ----------------
__device__ __forceinline__ void stage_rec(uint8_t* buf, const int8_t* spk, const int8_t* whhd,
                                          int m0, int n0, int k0B, int wid, int lane) {
#pragma unroll
    for (int i = 0; i < 2; ++i) {
        int c   = wid + i * 4;
        int row = c * 8 + (lane >> 3);
        int s   = (lane & 7) ^ (row & 7);
        gload((const uint8_t*)spk + (size_t)(m0 + row) * HH + k0B + (s << 4),
              buf + c * 1024);
    }
#pragma unroll
    for (int sub = 0; sub < 4; ++sub) {
        int row = sub * 8 + (lane >> 3);
        int s   = (lane & 7) ^ (row & 7);
        gload((const uint8_t*)whhd + (size_t)wid * WHH_PLANE +
              (size_t)(n0 + row) * HH + k0B + (s << 4),
              buf + 8192 + wid * 4096 + sub * 1024);
    }
}
__device__ __forceinline__ void stage_x(uint8_t* buf, const int8_t* xd_t, const int8_t* wihd,
                                        int m0, int n0, int k0B, int wid, int lane) {
#pragma unroll
    for (int sub = 0; sub < 4; ++sub) {
        int row = sub * 16 + (lane >> 2);
        int s   = ((lane & 3) - (row >> 1)) & 3;
        gload((const uint8_t*)xd_t + (size_t)wid * XD_PLANE +
              (size_t)(m0 + row) * NKP + k0B + (s << 4),
              buf + wid * 4096 + sub * 1024);
    }
#pragma unroll
    for (int i = 0; i < 2; ++i) {
        int cb  = wid + i * 4;
        int p   = cb >> 1, sub = cb & 1;
        int row = sub * 16 + (lane >> 2);
        int s   = ((lane & 3) - (row >> 1)) & 3;
        gload((const uint8_t*)wihd + (size_t)p * WIH_PLANE +
              (size_t)(n0 + row) * NKP + k0B + (s << 4),
              buf + 16384 + p * 2048 + sub * 1024);
    }
}

// ---------------- MFMA phases (validated; i32 accumulation exact/associative) ----------------
__device__ __forceinline__ void mfma_rec(const uint8_t* buf, int mw, int nw, int fr, int hi4,
                                         i32x4 aR[4][2]) {
#pragma unroll
    for (int ks = 0; ks < 2; ++ks) {
        int sl = ks * 4 + hi4;
        i32x4 a0 = ld_rec(buf, mw * 32 + fr,      sl);
        i32x4 a1 = ld_rec(buf, mw * 32 + 16 + fr, sl);
#pragma unroll
        for (int p = 0; p < 4; ++p) {
            i32x4 b = ld_rec(buf + 8192 + p * 4096, nw * 16 + fr, sl);
            aR[p][0] = __builtin_amdgcn_mfma_i32_16x16x64_i8(a0, b, aR[p][0], 0, 0, 0);
            aR[p][1] = __builtin_amdgcn_mfma_i32_16x16x64_i8(a1, b, aR[p][1], 0, 0, 0);
        }
    }
}
__device__ __forceinline__ void mfma_x(const uint8_t* buf, int mw, int nw, int fr, int hi4,
                                       i32x4 aX[5][2]) {
    i32x4 fa[4][2], fb[4];
#pragma unroll
    for (int p = 0; p < 4; ++p) {
        fa[p][0] = ld_x(buf + p * 4096, mw * 32 + fr,      hi4);
        fa[p][1] = ld_x(buf + p * 4096, mw * 32 + 16 + fr, hi4);
        fb[p]    = ld_x(buf + 16384 + p * 2048, nw * 16 + fr, hi4);
    }
#pragma unroll
    for (int a = 0; a < 4; ++a)
#pragma unroll
        for (int b = 0; b < 4; ++b) {
            if (a + b < 2) continue;
            const int c = a + b - 2;
            aX[c][0] = __builtin_amdgcn_mfma_i32_16x16x64_i8(fa[a][0], fb[b], aX[c][0], 0, 0, 0);
            aX[c][1] = __builtin_amdgcn_mfma_i32_16x16x64_i8(fa[a][1], fb[b], aX[c][1], 0, 0, 0);
        }
}

// ---------------- conversion kernels (unchanged, validated) ----------------
__global__ __launch_bounds__(256) void conv_whh_i8(const float* __restrict__ W,
                                                   int8_t* __restrict__ p0, int8_t* __restrict__ p1,
                                                   int8_t* __restrict__ p2, int8_t* __restrict__ p3,
                                                   const float* __restrict__ tau_h,
                                                   const float* __restrict__ tau_o,
                                                   float* __restrict__ alpha) {
    int idx = blockIdx.x * 256 + threadIdx.x;
    if (idx == 0) {
        float qh = __fdiv_rn(-1.0f, tau_h[0]);
        float qo = __fdiv_rn(-1.0f, tau_o[0]);
        alpha[0] = (float)exp((double)qh);
        alpha[1] = (float)exp((double)qo);
    }
    float4 v = reinterpret_cast<const float4*>(W)[idx];
    signed char dx[4], dy[4], dz[4], dw[4];
    const double SC = 1073741824.0;  // 2^30
    wdig(v.x, SC, dx); wdig(v.y, SC, dy); wdig(v.z, SC, dz); wdig(v.w, SC, dw);
    reinterpret_cast<char4*>(p0)[idx] = make_char4(dx[0], dy[0], dz[0], dw[0]);
    reinterpret_cast<char4*>(p1)[idx] = make_char4(dx[1], dy[1], dz[1], dw[1]);
    reinterpret_cast<char4*>(p2)[idx] = make_char4(dx[2], dy[2], dz[2], dw[2]);
    reinterpret_cast<char4*>(p3)[idx] = make_char4(dx[3], dy[3], dz[3], dw[3]);
}

__global__ __launch_bounds__(256) void conv_wih_i8(const float* __restrict__ W,
                                                   int8_t* __restrict__ p0, int8_t* __restrict__ p1,
                                                   int8_t* __restrict__ p2, int8_t* __restrict__ p3) {
    int row = blockIdx.x;
    for (int i = threadIdx.x; i < NKP; i += 256) {
        float v = (i < NIN) ? W[(size_t)row * NIN + i] : 0.f;
        signed char d[4];
        wdig(v, 1073741824.0, d);        // 2^30
        size_t o = (size_t)row * NKP + i;
        p0[o] = d[0]; p1[o] = d[1]; p2[o] = d[2]; p3[o] = d[3];
    }
}

__global__ __launch_bounds__(256) void conv_x_i8(const float* __restrict__ in,
                                                 int8_t* __restrict__ p0, int8_t* __restrict__ p1,
                                                 int8_t* __restrict__ p2, int8_t* __restrict__ p3) {
    int blk = blockIdx.x;
    int t = blk >> 8, b = blk & 255;
    const float* src = in + ((size_t)b * TT + t) * NIN;   // input [B,T,N]
    size_t dst = ((size_t)t * BB + b) * NKP;              // digits [T,B,NKP]
    for (int i = threadIdx.x; i < NKP; i += 256) {
        float v = (i < NIN) ? src[i] : 0.f;
        signed char d[4];
        wdig(v, 16777216.0, d);          // 2^24
        p0[dst + i] = d[0]; p1[dst + i] = d[1]; p2[dst + i] = d[2]; p3[dst + i] = d[3];
    }
}

// ---------------- hoisted x-projection GEMM (bit-identical combine; XCD-swizzled) ----------------
__global__ __launch_bounds__(256, 2) void xproj_kernel(const int8_t* __restrict__ xd,
                                                       const int8_t* __restrict__ wihd,
                                                       float* __restrict__ xp) {
    __shared__ __align__(16) uint8_t X0[24576];
    __shared__ __align__(16) uint8_t X1[24576];
    __shared__ __align__(16) uint8_t X2[24576];

    // swizzle: same-(t,m) A-tile -> 64 blocks on ONE XCD, co-resident; nh outer halves wih working set
    int bid = blockIdx.x;                    // 16384
    int xcd = bid & 7;
    int r   = bid >> 3;                      // 0..2047
    int jn  = r & 31;
    int gm  = (r >> 5) & 31;
    int nh  = r >> 10;                       // 0..1
    int grp = xcd + 8 * gm;                  // 0..255 = (t,m)
    int t   = grp >> 2;
    int m0  = (grp & 3) * 64;
    int n0  = (nh * 32 + jn) * 32;

    int tid = threadIdx.x;
    int lane = tid & 63, wid = tid >> 6;
    int mw = wid >> 1, nw = wid & 1;
    int fr = lane & 15, hi4 = lane >> 4;

    const int8_t* xd_t = xd + (size_t)t * BB * NKP;
    i32x4 aX[5][2] = {};

    stage_x(X0, xd_t, wihd, m0, n0, 0,  wid, lane);
    stage_x(X1, xd_t, wihd, m0, n0, 64, wid, lane);
#pragma unroll
    for (int j = 0; j < XNIT; ++j) {
        if (j <= XNIT - 2) { WAIT_VM6(); } else { WAIT_VM0(); }
        SCHED0();
        __builtin_amdgcn_s_barrier();
        if (j + 2 < XNIT) {
            uint8_t* nb = ((j + 2) % 3 == 0) ? X0 : ((j + 2) % 3 == 1) ? X1 : X2;
            stage_x(nb, xd_t, wihd, m0, n0, (j + 2) * 64, wid, lane);
        }
        const uint8_t* cb = (j % 3 == 0) ? X0 : (j % 3 == 1) ? X1 : X2;
        __builtin_amdgcn_s_setprio(1);
        mfma_x(cb, mw, nw, fr, hi4, aX);
        __builtin_amdgcn_s_setprio(0);
    }

    int jcol = n0 + nw * 16 + fr;
    int rq = hi4 * 4;
    float* xp_t = xp + (size_t)t * BB * HH;
#pragma unroll
    for (int msub = 0; msub < 2; ++msub)
#pragma unroll
        for (int rr = 0; rr < 4; ++rr) {
            int b = m0 + mw * 32 + msub * 16 + rq + rr;
            double xp64 = (double)aX[4][msub][rr] * 0x1p-6
                        + (double)aX[3][msub][rr] * 0x1p-14
                        + (double)aX[2][msub][rr] * 0x1p-22
                        + (double)aX[1][msub][rr] * 0x1p-30
                        + (double)aX[0][msub][rr] * 0x1p-38;
            xp_t[(size_t)b * HH + jcol] = (float)xp64;
        }
}

// ---------------- output-LIF: block g owns batch b=g; wave wid handles outputs wid*5..wid*5+4 ----------------
// Per-pair math identical to validated round-8 o_dot_wave (lane k-order sum + f64 butterfly).
__device__ __forceinline__ void odot_block(int g, int wid, int lane, const int8_t* __restrict__ spk,
                                           const float* __restrict__ W_ho,
                                           const float* __restrict__ b_ho,
                                           float a_o, float* __restrict__ o_mem,
                                           float* __restrict__ o_spk, float* __restrict__ o_sum,
                                           float* __restrict__ out /*nullptr unless final*/) {
    const int8_t* srow = spk + (size_t)g * HH + lane * 32;
    int4 s0 = *reinterpret_cast<const int4*>(srow);
    int4 s1 = *reinterpret_cast<const int4*>(srow + 16);
    int sw[8] = {s0.x, s0.y, s0.z, s0.w, s1.x, s1.y, s1.z, s1.w};
#pragma unroll 1
    for (int p = 0; p < 5; ++p) {
        int o = wid * 5 + p;
        const float* wrow = W_ho + (size_t)o * HH + lane * 32;
        double acc = 0.0;
#pragma unroll
        for (int q = 0; q < 8; ++q) {
            float4 w = *reinterpret_cast<const float4*>(wrow + q * 4);
            int sv = sw[q];
            acc += (sv & 0x000000FF) ? (double)w.x : 0.0;
            acc += (sv & 0x0000FF00) ? (double)w.y : 0.0;
            acc += (sv & 0x00FF0000) ? (double)w.z : 0.0;
            acc += (sv & 0xFF000000) ? (double)w.w : 0.0;
        }
#pragma unroll
        for (int off = 32; off >= 1; off >>= 1)
            acc += __shfl_xor(acc, off, 64);
        if (lane == 0) {
            float dot = (float)acc;
            size_t oo = (size_t)g * OO + o;
            float om = o_mem[oo], osp = o_spk[oo];
            float v = __fadd_rn(__fadd_rn(__fmul_rn(__fmul_rn(om, a_o), 1.f - osp), dot), b_ho[o]);
            float sn = (v > THRESH_V) ? 1.f : 0.f;
            o_mem[oo] = v;
            o_spk[oo] = sn;
            float s = __fadd_rn(o_sum[oo], sn);
            o_sum[oo] = s;
            if (out) out[oo] = __fmul_rn(s, 1.f / 64.f);
        }
    }
}

// ---------------- persistent kernel: all 64 steps, grid barrier between steps ----------------
// 256 blocks x 96KB LDS -> exactly 1 block/CU on 256 CUs: co-residency is structural (no deadlock).
__global__ __launch_bounds__(256) void persist_kernel(
    const int8_t* __restrict__ whhd, const float* __restrict__ xp,
    int8_t* __restrict__ spk0, int8_t* __restrict__ spk1,
    float* __restrict__ h_mem, const float* __restrict__ alpha,
    const float* __restrict__ b_ih, const float* __restrict__ b_hh,
    const float* __restrict__ W_ho, const float* __restrict__ b_ho,
    float* __restrict__ o_mem, float* __restrict__ o_spk, float* __restrict__ o_sum,
    float* __restrict__ out, int* __restrict__ bar) {
    __shared__ __align__(16) uint8_t L0[24576];
    __shared__ __align__(16) uint8_t L1[24576];
    __shared__ __align__(16) uint8_t L2[24576];
    __shared__ __align__(16) uint8_t L3[24576];

    int g   = blockIdx.x;                // 0..255; fixed (m,n) tile + batch g for o-path
    int tid = threadIdx.x;
    int lane = tid & 63, wid = tid >> 6;
    int m0 = (g >> 6) * 64;
    int n0 = (g & 63) * 32;              // same-n blocks 64 apart -> same XCD (whh L2 locality)
    int mw = wid >> 1, nw = wid & 1;
    int fr = lane & 15, hi4 = lane >> 4;

    float a_h = alpha[0], a_o = alpha[1];
    int* cnt  = bar;
    int* flag = bar + 32;                // separate cacheline

#pragma unroll 1
    for (int t = 0; t < TT; ++t) {
        const int8_t* srd = (t & 1) ? spk1 : spk0;
        int8_t*       swr = (t & 1) ? spk0 : spk1;

        // output-LIF for step t-1 (spikes = srd, visible since last barrier)
        if (t > 0) {
            odot_block(g, wid, lane, srd, W_ho, b_ho, a_o, o_mem, o_spk, o_sum, nullptr);
            SCHED0();
        }

        // ---- rec GEMM pipeline (validated structure, depth-3, counted vmcnt) ----
        i32x4 aR[4][2] = {};
        stage_rec(L0, srd, whhd, m0, n0, 0,   wid, lane);
        stage_rec(L1, srd, whhd, m0, n0, 128, wid, lane);
        stage_rec(L2, srd, whhd, m0, n0, 256, wid, lane);
#pragma unroll
        for (int h = 0; h < NREC; ++h) {
            if (h <= NREC - 3) { WAIT_VM12(); }
            else if (h == NREC - 2) { WAIT_VM6(); }
            else { WAIT_VM0(); }
            SCHED0();
            __builtin_amdgcn_s_barrier();
            if (h + 3 < NREC) {
                uint8_t* nb = ((h + 3) & 3) == 0 ? L0 : ((h + 3) & 3) == 1 ? L1
                            : ((h + 3) & 3) == 2 ? L2 : L3;
                stage_rec(nb, srd, whhd, m0, n0, (h + 3) * 128, wid, lane);
            }
            const uint8_t* cb = (h & 3) == 0 ? L0 : (h & 3) == 1 ? L1
                              : (h & 3) == 2 ? L2 : L3;
            __builtin_amdgcn_s_setprio(1);
            mfma_rec(cb, mw, nw, fr, hi4, aR);
            __builtin_amdgcn_s_setprio(0);
        }

        // ---- epilogue: LIF update, np's exact op order (validated) ----
        const float* xp_t = xp + (size_t)t * BB * HH;
        int j  = n0 + nw * 16 + fr;
        int rq = hi4 * 4;
#pragma unroll
        for (int msub = 0; msub < 2; ++msub)
#pragma unroll
            for (int rr = 0; rr < 4; ++rr) {
                int b = m0 + mw * 32 + msub * 16 + rq + rr;
                size_t off = (size_t)b * HH + j;
                float recf = (float)((double)aR[3][msub][rr] * 0x1p-6
                                   + (double)aR[2][msub][rr] * 0x1p-14
                                   + (double)aR[1][msub][rr] * 0x1p-22
                                   + (double)aR[0][msub][rr] * 0x1p-30);
                float xpf = xp_t[off];
                float xpb = __fadd_rn(xpf, b_ih[j]);
                float hv  = h_mem[off];
                float keep = srd[off] ? 0.f : 1.f;
                float v = __fadd_rn(__fmul_rn(__fmul_rn(hv, a_h), keep), xpb);
                v = __fadd_rn(v, recf);
                v = __fadd_rn(v, b_hh[j]);
                h_mem[off] = v;
                swr[off] = (v > THRESH_V) ? (int8_t)1 : (int8_t)0;
            }

        // ---- grid barrier: arrive (atomic) + last-arriver broadcasts flag ----
        __syncthreads();                              // all waves' stores drained (waitcnt before s_barrier)
        if (tid == 0) {
            __threadfence();                          // release spk writes device-wide
            int old = atomicAdd(cnt, 1);
            if (old == NBLK * (t + 1) - 1) {
                __hip_atomic_store(flag, t + 1, __ATOMIC_RELEASE, __HIP_MEMORY_SCOPE_AGENT);
            } else {
                while (__hip_atomic_load(flag, __ATOMIC_RELAXED, __HIP_MEMORY_SCOPE_AGENT) < t + 1)
                    __builtin_amdgcn_s_sleep(8);
            }
        }
        __syncthreads();
        __threadfence();                              // acquire: invalidate stale L1/L2 spk lines
    }

    // final output-LIF for t=63 (spikes in spk0) + write normalized output
    odot_block(g, wid, lane, spk0, W_ho, b_ho, a_o, o_mem, o_spk, o_sum, out);
}

// ---------------- host ----------------
extern "C" void kernel_launch(void* const* d_in, const int* in_sizes, int n_in,
                              void* d_out, int out_size, void* d_ws, size_t ws_size,
                              hipStream_t stream) {
    const float* in    = (const float*)d_in[0];
    const float* W_ih  = (const float*)d_in[1];
    const float* b_ih  = (const float*)d_in[2];
    const float* W_hh  = (const float*)d_in[3];
    const float* b_hh  = (const float*)d_in[4];
    const float* W_ho  = (const float*)d_in[5];
    const float* b_ho  = (const float*)d_in[6];
    const float* tau_h = (const float*)d_in[7];
    const float* tau_o = (const float*)d_in[8];

    uint8_t* ws = (uint8_t*)d_ws;
    float*  h_mem = (float*)(ws + OFF_HMEM);
    int8_t* spk0  = (int8_t*)(ws + OFF_SPK0);
    float*  o_mem = (float*)(ws + OFF_OMEM);
    float*  o_spk = (float*)(ws + OFF_OSPK);
    float*  o_sum = (float*)(ws + OFF_OSUM);
    int*    bar   = (int*)(ws + OFF_BAR);
    int8_t* spk1  = (int8_t*)(ws + OFF_SPK1);
    float*  alpha = (float*)(ws + OFF_ALPHA);
    int8_t* whhd  = (int8_t*)(ws + OFF_WHHD);
    int8_t* wihd  = (int8_t*)(ws + OFF_WIHD);
    int8_t* xd    = (int8_t*)(ws + OFF_XD);
    float*  xp    = (float*)(ws + OFF_XP);

    if (ws_size < WS_NEED) return;  // insufficient scratch -> output stays poison (diagnostic)

    hipMemsetAsync(ws, 0, ZERO_END, stream);   // zeroes state + barrier counters every launch/replay
    conv_whh_i8<<<4096, 256, 0, stream>>>(W_hh,
                                          whhd, whhd + WHH_PLANE, whhd + 2 * WHH_PLANE, whhd + 3 * WHH_PLANE,
                                          tau_h, tau_o, alpha);
    conv_wih_i8<<<2048, 256, 0, stream>>>(W_ih,
                                          wihd, wihd + WIH_PLANE, wihd + 2 * WIH_PLANE, wihd + 3 * WIH_PLANE);
    conv_x_i8<<<16384, 256, 0, stream>>>(in,
                                         xd, xd + XD_PLANE, xd + 2 * XD_PLANE, xd + 3 * XD_PLANE);
    xproj_kernel<<<16384, 256, 0, stream>>>(xd, wihd, xp);

    persist_kernel<<<NBLK, 256, 0, stream>>>(whhd, xp, spk0, spk1, h_mem, alpha,
                                             b_ih, b_hh, W_ho, b_ho,
                                             o_mem, o_spk, o_sum, (float*)d_out, bar);
}

// Round 11
// 1541.455 us; speedup vs baseline: 2.0272x; 2.0272x over previous
//
#include <hip/hip_runtime.h>
#include <stdint.h>

typedef __attribute__((ext_vector_type(4))) int i32x4;

static constexpr int BB = 256, TT = 64, NIN = 700, NKP = 768, HH = 2048, OO = 20;
static constexpr float THRESH_V = 0.3f;
static constexpr int NBLK = 256;                 // 4 m-tiles (M64) x 64 n-tiles (N32); block g also owns batch g's o-dots
static constexpr int NREC = 16;                  // rec K-chunks (128B each -> K=2048)
static constexpr int XNIT = 11;                  // x K-chunks (64B each -> K=704 >= 700; rest zero-pad, exact skip)
static constexpr int NIT  = NREC + XNIT;         // 27

// ---------------- ws layout (bytes) ---- validated round-5 layout ----------------
static constexpr size_t OFF_HMEM  = 0;           // 256*2048*4
static constexpr size_t OFF_SPK0  = 2097152;     // 256*2048*1 (i8)
static constexpr size_t OFF_OMEM  = 2621440;
static constexpr size_t OFF_OSPK  = 2641920;
static constexpr size_t OFF_OSUM  = 2662400;
static constexpr size_t ZERO_END  = 2682880;     // memset [0, ZERO_END) every launch
static constexpr size_t OFF_SPK1  = 2682880;
static constexpr size_t OFF_ALPHA = 3207168;
static constexpr size_t OFF_WHHD  = 3207424;     // 4 planes x 2048*2048 i8
static constexpr size_t WHH_PLANE = 4194304;
static constexpr size_t OFF_WIHD  = 19984640;    // 4 planes x 2048*768 i8
static constexpr size_t WIH_PLANE = 1572864;
static constexpr size_t OFF_XD    = 26276096;    // 4 planes x 64*256*768 i8
static constexpr size_t XD_PLANE  = 12582912;
static constexpr size_t WS_NEED   = 76607744;    // known-OK since round 4
// ---------------- sync primitives ----------------
#define WAIT_VM12() asm volatile("s_waitcnt vmcnt(12)" ::: "memory")
#define WAIT_VM6()  asm volatile("s_waitcnt vmcnt(6)" ::: "memory")
#define WAIT_VM0()  asm volatile("s_waitcnt vmcnt(0)" ::: "memory")
#define SCHED0()    __builtin_amdgcn_sched_barrier(0)

// ---------------- digit helpers (identical to validated round 5) ----------------
__device__ __forceinline__ void wdig(float w, double scale, signed char d[4]) {
    int q = (int)rint((double)w * scale);
    int t0 = (int)(signed char)(q & 0xFF); q = (q - t0) >> 8;
    int t1 = (int)(signed char)(q & 0xFF); q = (q - t1) >> 8;
    int t2 = (int)(signed char)(q & 0xFF); q = (q - t2) >> 8;
    d[0] = (signed char)t0; d[1] = (signed char)t1;
    d[2] = (signed char)t2; d[3] = (signed char)q;
}

// ---------------- LDS fragment reads (validated) ----------------
__device__ __forceinline__ i32x4 ld_rec(const uint8_t* base, int row, int sl) {
    return *reinterpret_cast<const i32x4*>(base + row * 128 + ((sl ^ (row & 7)) << 4));
}
__device__ __forceinline__ i32x4 ld_x(const uint8_t* base, int row, int s) {
    int phys = (s + (row >> 1)) & 3;
    return *reinterpret_cast<const i32x4*>(base + row * 64 + (phys << 4));
}

__device__ __forceinline__ void gload(const uint8_t* src, uint8_t* dst) {
    __builtin_amdgcn_global_load_lds((const __attribute__((address_space(1))) void*)src,
                                     (__attribute__((address_space(3))) void*)dst, 16, 0, 0);
}

// ---------------- stage one 24KB chunk (6 gload_lds per wave, uniform; validated) ----------------
__device__ __forceinline__ void stage_rec(uint8_t* buf, const int8_t* spk, const int8_t* whhd,
                                          int m0, int n0, int k0B, int wid, int lane) {
#pragma unroll
    for (int i = 0; i < 2; ++i) {
        int c   = wid + i * 4;
        int row = c * 8 + (lane >> 3);
        int s   = (lane & 7) ^ (row & 7);
        gload((const uint8_t*)spk + (size_t)(m0 + row) * HH + k0B + (s << 4),
              buf + c * 1024);
    }
#pragma unroll
    for (int sub = 0; sub < 4; ++sub) {
        int row = sub * 8 + (lane >> 3);
        int s   = (lane & 7) ^ (row & 7);
        gload((const uint8_t*)whhd + (size_t)wid * WHH_PLANE +
              (size_t)(n0 + row) * HH + k0B + (s << 4),
              buf + 8192 + wid * 4096 + sub * 1024);
    }
}
__device__ __forceinline__ void stage_x(uint8_t* buf, const int8_t* xd_t, const int8_t* wihd,
                                        int m0, int n0, int k0B, int wid, int lane) {
#pragma unroll
    for (int sub = 0; sub < 4; ++sub) {
        int row = sub * 16 + (lane >> 2);
        int s   = ((lane & 3) - (row >> 1)) & 3;
        gload((const uint8_t*)xd_t + (size_t)wid * XD_PLANE +
              (size_t)(m0 + row) * NKP + k0B + (s << 4),
              buf + wid * 4096 + sub * 1024);
    }
#pragma unroll
    for (int i = 0; i < 2; ++i) {
        int cb  = wid + i * 4;
        int p   = cb >> 1, sub = cb & 1;
        int row = sub * 16 + (lane >> 2);
        int s   = ((lane & 3) - (row >> 1)) & 3;
        gload((const uint8_t*)wihd + (size_t)p * WIH_PLANE +
              (size_t)(n0 + row) * NKP + k0B + (s << 4),
              buf + 16384 + p * 2048 + sub * 1024);
    }
}

// ---------------- MFMA phases (validated; i32 accumulation exact/associative) ----------------
__device__ __forceinline__ void mfma_rec(const uint8_t* buf, int mw, int nw, int fr, int hi4,
                                         i32x4 aR[4][2]) {
#pragma unroll
    for (int ks = 0; ks < 2; ++ks) {
        int sl = ks * 4 + hi4;
        i32x4 a0 = ld_rec(buf, mw * 32 + fr,      sl);
        i32x4 a1 = ld_rec(buf, mw * 32 + 16 + fr, sl);
#pragma unroll
        for (int p = 0; p < 4; ++p) {
            i32x4 b = ld_rec(buf + 8192 + p * 4096, nw * 16 + fr, sl);
            aR[p][0] = __builtin_amdgcn_mfma_i32_16x16x64_i8(a0, b, aR[p][0], 0, 0, 0);
            aR[p][1] = __builtin_amdgcn_mfma_i32_16x16x64_i8(a1, b, aR[p][1], 0, 0, 0);
        }
    }
}
__device__ __forceinline__ void mfma_x(const uint8_t* buf, int mw, int nw, int fr, int hi4,
                                       i32x4 aX[5][2]) {
    i32x4 fa[4][2], fb[4];
#pragma unroll
    for (int p = 0; p < 4; ++p) {
        fa[p][0] = ld_x(buf + p * 4096, mw * 32 + fr,      hi4);
        fa[p][1] = ld_x(buf + p * 4096, mw * 32 + 16 + fr, hi4);
        fb[p]    = ld_x(buf + 16384 + p * 2048, nw * 16 + fr, hi4);
    }
#pragma unroll
    for (int a = 0; a < 4; ++a)
#pragma unroll
        for (int b = 0; b < 4; ++b) {
            if (a + b < 2) continue;                 // dropped terms ~2e-9 rms (validated)
            const int c = a + b - 2;
            aX[c][0] = __builtin_amdgcn_mfma_i32_16x16x64_i8(fa[a][0], fb[b], aX[c][0], 0, 0, 0);
            aX[c][1] = __builtin_amdgcn_mfma_i32_16x16x64_i8(fa[a][1], fb[b], aX[c][1], 0, 0, 0);
        }
}

// ---------------- conversion kernels (unchanged, validated) ----------------
__global__ __launch_bounds__(256) void conv_whh_i8(const float* __restrict__ W,
                                                   int8_t* __restrict__ p0, int8_t* __restrict__ p1,
                                                   int8_t* __restrict__ p2, int8_t* __restrict__ p3,
                                                   const float* __restrict__ tau_h,
                                                   const float* __restrict__ tau_o,
                                                   float* __restrict__ alpha) {
    int idx = blockIdx.x * 256 + threadIdx.x;
    if (idx == 0) {
        float qh = __fdiv_rn(-1.0f, tau_h[0]);
        float qo = __fdiv_rn(-1.0f, tau_o[0]);
        alpha[0] = (float)exp((double)qh);
        alpha[1] = (float)exp((double)qo);
    }
    float4 v = reinterpret_cast<const float4*>(W)[idx];
    signed char dx[4], dy[4], dz[4], dw[4];
    const double SC = 1073741824.0;  // 2^30
    wdig(v.x, SC, dx); wdig(v.y, SC, dy); wdig(v.z, SC, dz); wdig(v.w, SC, dw);
    reinterpret_cast<char4*>(p0)[idx] = make_char4(dx[0], dy[0], dz[0], dw[0]);
    reinterpret_cast<char4*>(p1)[idx] = make_char4(dx[1], dy[1], dz[1], dw[1]);
    reinterpret_cast<char4*>(p2)[idx] = make_char4(dx[2], dy[2], dz[2], dw[2]);
    reinterpret_cast<char4*>(p3)[idx] = make_char4(dx[3], dy[3], dz[3], dw[3]);
}

__global__ __launch_bounds__(256) void conv_wih_i8(const float* __restrict__ W,
                                                   int8_t* __restrict__ p0, int8_t* __restrict__ p1,
                                                   int8_t* __restrict__ p2, int8_t* __restrict__ p3) {
    int row = blockIdx.x;
    for (int i = threadIdx.x; i < NKP; i += 256) {
        float v = (i < NIN) ? W[(size_t)row * NIN + i] : 0.f;
        signed char d[4];
        wdig(v, 1073741824.0, d);        // 2^30
        size_t o = (size_t)row * NKP + i;
        p0[o] = d[0]; p1[o] = d[1]; p2[o] = d[2]; p3[o] = d[3];
    }
}

__global__ __launch_bounds__(256) void conv_x_i8(const float* __restrict__ in,
                                                 int8_t* __restrict__ p0, int8_t* __restrict__ p1,
                                                 int8_t* __restrict__ p2, int8_t* __restrict__ p3) {
    int blk = blockIdx.x;
    int t = blk >> 8, b = blk & 255;
    const float* src = in + ((size_t)b * TT + t) * NIN;   // input [B,T,N]
    size_t dst = ((size_t)t * BB + b) * NKP;              // digits [T,B,NKP]
    for (int i = threadIdx.x; i < NKP; i += 256) {
        float v = (i < NIN) ? src[i] : 0.f;
        signed char d[4];
        wdig(v, 16777216.0, d);          // 2^24
        p0[dst + i] = d[0]; p1[dst + i] = d[1]; p2[dst + i] = d[2]; p3[dst + i] = d[3];
    }
}

// ---------------- output-LIF: block g owns batch g; wave wid -> outputs wid*5..wid*5+4 ----------------
// Per-pair math identical to validated round-8 o_dot_wave (lane k-slice sum + f64 butterfly).
__device__ __forceinline__ void odot_block(int g, int wid, int lane, const int8_t* __restrict__ spk,
                                           const float* __restrict__ W_ho,
                                           const float* __restrict__ b_ho,
                                           float a_o, float* __restrict__ o_mem,
                                           float* __restrict__ o_spk, float* __restrict__ o_sum,
                                           float* __restrict__ out /*nullptr unless final*/) {
    const int8_t* srow = spk + (size_t)g * HH + lane * 32;
    int4 s0 = *reinterpret_cast<const int4*>(srow);
    int4 s1 = *reinterpret_cast<const int4*>(srow + 16);
    int sw[8] = {s0.x, s0.y, s0.z, s0.w, s1.x, s1.y, s1.z, s1.w};
#pragma unroll 1
    for (int p = 0; p < 5; ++p) {
        int o = wid * 5 + p;
        const float* wrow = W_ho + (size_t)o * HH + lane * 32;
        double acc = 0.0;
#pragma unroll
        for (int q = 0; q < 8; ++q) {
            float4 w = *reinterpret_cast<const float4*>(wrow + q * 4);
            int sv = sw[q];
            acc += (sv & 0x000000FF) ? (double)w.x : 0.0;
            acc += (sv & 0x0000FF00) ? (double)w.y : 0.0;
            acc += (sv & 0x00FF0000) ? (double)w.z : 0.0;
            acc += (sv & 0xFF000000) ? (double)w.w : 0.0;
        }
#pragma unroll
        for (int off = 32; off >= 1; off >>= 1)
            acc += __shfl_xor(acc, off, 64);
        if (lane == 0) {
            float dot = (float)acc;
            size_t oo = (size_t)g * OO + o;
            float om = o_mem[oo], osp = o_spk[oo];
            float v = __fadd_rn(__fadd_rn(__fmul_rn(__fmul_rn(om, a_o), 1.f - osp), dot), b_ho[o]);
            float sn = (v > THRESH_V) ? 1.f : 0.f;
            o_mem[oo] = v;
            o_spk[oo] = sn;
            float s = __fadd_rn(o_sum[oo], sn);
            o_sum[oo] = s;
            if (out) out[oo] = __fmul_rn(s, 1.f / 64.f);
        }
    }
}

// ---------------- per-step kernel: 256 blocks, mixed 27-chunk pipeline + inline o-dot ----------------
__global__ __launch_bounds__(256) void step_kernel(
    const int8_t* __restrict__ whhd, const int8_t* __restrict__ wihd,
    const int8_t* __restrict__ xd,
    const int8_t* __restrict__ spk_rd, int8_t* __restrict__ spk_wr,
    float* __restrict__ h_mem, const float* __restrict__ alpha,
    const float* __restrict__ b_ih, const float* __restrict__ b_hh,
    const float* __restrict__ W_ho, const float* __restrict__ b_ho,
    float* __restrict__ o_mem, float* __restrict__ o_spk, float* __restrict__ o_sum,
    int t) {
    // four statically-named 24KB buffers -> depth-3 prefetch, counted vmcnt survives
    __shared__ __align__(16) uint8_t L0[24576];
    __shared__ __align__(16) uint8_t L1[24576];
    __shared__ __align__(16) uint8_t L2[24576];
    __shared__ __align__(16) uint8_t L3[24576];

    int g   = blockIdx.x;                // 0..255
    int tid = threadIdx.x;
    int lane = tid & 63, wid = tid >> 6;
    int m0 = (g >> 6) * 64;              // 4 m-tiles of 64 batches
    int n0 = (g & 63) * 32;              // 64 n-tiles; same-n blocks 64 apart -> same XCD
    int mw = wid >> 1, nw = wid & 1;     // wave covers 32m x 16n
    int fr = lane & 15, hi4 = lane >> 4;

    const int8_t* xd_t = xd + (size_t)t * BB * NKP;

    i32x4 aR[4][2] = {};                 // rec digit accumulators [plane][msub]
    i32x4 aX[5][2] = {};                 // x digit-pair accumulators [a+b-2][msub]

    // prologue: 3 chunks in flight (18 loads/wave)
    stage_rec(L0, spk_rd, whhd, m0, n0, 0,   wid, lane);
    stage_rec(L1, spk_rd, whhd, m0, n0, 128, wid, lane);
    stage_rec(L2, spk_rd, whhd, m0, n0, 256, wid, lane);

#pragma unroll
    for (int h = 0; h < NIT; ++h) {
        if (h <= NIT - 3) { WAIT_VM12(); }
        else if (h == NIT - 2) { WAIT_VM6(); }
        else { WAIT_VM0(); }             // chunk h's 6 loads complete
        SCHED0();
        __builtin_amdgcn_s_barrier();    // all waves have chunk h; mfma(h-1) reads done
        if (h + 3 < NIT) {               // stage chunk h+3 into L[(h+3)&3]
            uint8_t* nb = ((h + 3) & 3) == 0 ? L0 : ((h + 3) & 3) == 1 ? L1
                        : ((h + 3) & 3) == 2 ? L2 : L3;
            int c = h + 3;
            if (c < NREC) stage_rec(nb, spk_rd, whhd, m0, n0, c * 128, wid, lane);
            else          stage_x(nb, xd_t, wihd, m0, n0, (c - NREC) * 64, wid, lane);
        }
        const uint8_t* cb = (h & 3) == 0 ? L0 : (h & 3) == 1 ? L1
                          : (h & 3) == 2 ? L2 : L3;
        __builtin_amdgcn_s_setprio(1);
        if (h < NREC) mfma_rec(cb, mw, nw, fr, hi4, aR);
        else          mfma_x(cb, mw, nw, fr, hi4, aX);
        __builtin_amdgcn_s_setprio(0);
    }

    // ---- epilogue: LIF update, np's exact op order (validated round 5) ----
    float a_h = alpha[0];
    int j  = n0 + nw * 16 + fr;
    int rq = hi4 * 4;
#pragma unroll
    for (int msub = 0; msub < 2; ++msub)
#pragma unroll
        for (int rr = 0; rr < 4; ++rr) {
            int b = m0 + mw * 32 + msub * 16 + rq + rr;
            size_t off = (size_t)b * HH + j;
            float recf = (float)((double)aR[3][msub][rr] * 0x1p-6
                               + (double)aR[2][msub][rr] * 0x1p-14
                               + (double)aR[1][msub][rr] * 0x1p-22
                               + (double)aR[0][msub][rr] * 0x1p-30);
            double xp64 = (double)aX[4][msub][rr] * 0x1p-6
                        + (double)aX[3][msub][rr] * 0x1p-14
                        + (double)aX[2][msub][rr] * 0x1p-22
                        + (double)aX[1][msub][rr] * 0x1p-30
                        + (double)aX[0][msub][rr] * 0x1p-38;
            float xpf = (float)xp64;
            float xpb = __fadd_rn(xpf, b_ih[j]);
            float hv  = h_mem[off];
            float keep = spk_rd[off] ? 0.f : 1.f;
            float v = __fadd_rn(__fmul_rn(__fmul_rn(hv, a_h), keep), xpb);
            v = __fadd_rn(v, recf);
            v = __fadd_rn(v, b_hh[j]);
            h_mem[off] = v;
            spk_wr[off] = (v > THRESH_V) ? (int8_t)1 : (int8_t)0;
        }

    // ---- inline output-LIF for step t-1 (spikes = spk_rd); no extra blocks, no tail ----
    if (t > 0)
        odot_block(g, wid, lane, spk_rd, W_ho, b_ho, alpha[1], o_mem, o_spk, o_sum, nullptr);
}

__global__ __launch_bounds__(256) void final_kernel(const int8_t* __restrict__ spk,
                                                    const float* __restrict__ W_ho,
                                                    const float* __restrict__ b_ho,
                                                    const float* __restrict__ alpha,
                                                    float* __restrict__ o_mem,
                                                    float* __restrict__ o_spk,
                                                    float* __restrict__ o_sum,
                                                    float* __restrict__ out) {
    int lane = threadIdx.x & 63, wid = threadIdx.x >> 6;
    odot_block(blockIdx.x, wid, lane, spk, W_ho, b_ho, alpha[1], o_mem, o_spk, o_sum, out);
}

// ---------------- host ----------------
extern "C" void kernel_launch(void* const* d_in, const int* in_sizes, int n_in,
                              void* d_out, int out_size, void* d_ws, size_t ws_size,
                              hipStream_t stream) {
    const float* in    = (const float*)d_in[0];
    const float* W_ih  = (const float*)d_in[1];
    const float* b_ih  = (const float*)d_in[2];
    const float* W_hh  = (const float*)d_in[3];
    const float* b_hh  = (const float*)d_in[4];
    const float* W_ho  = (const float*)d_in[5];
    const float* b_ho  = (const float*)d_in[6];
    const float* tau_h = (const float*)d_in[7];
    const float* tau_o = (const float*)d_in[8];

    uint8_t* ws = (uint8_t*)d_ws;
    float*  h_mem = (float*)(ws + OFF_HMEM);
    int8_t* spk0  = (int8_t*)(ws + OFF_SPK0);
    float*  o_mem = (float*)(ws + OFF_OMEM);
    float*  o_spk = (float*)(ws + OFF_OSPK);
    float*  o_sum = (float*)(ws + OFF_OSUM);
    int8_t* spk1  = (int8_t*)(ws + OFF_SPK1);
    float*  alpha = (float*)(ws + OFF_ALPHA);
    int8_t* whhd  = (int8_t*)(ws + OFF_WHHD);
    int8_t* wihd  = (int8_t*)(ws + OFF_WIHD);
    int8_t* xd    = (int8_t*)(ws + OFF_XD);

    if (ws_size < WS_NEED) return;  // insufficient scratch -> output stays poison (diagnostic)

    hipMemsetAsync(ws, 0, ZERO_END, stream);
    conv_whh_i8<<<4096, 256, 0, stream>>>(W_hh,
                                          whhd, whhd + WHH_PLANE, whhd + 2 * WHH_PLANE, whhd + 3 * WHH_PLANE,
                                          tau_h, tau_o, alpha);
    conv_wih_i8<<<2048, 256, 0, stream>>>(W_ih,
                                          wihd, wihd + WIH_PLANE, wihd + 2 * WIH_PLANE, wihd + 3 * WIH_PLANE);
    conv_x_i8<<<16384, 256, 0, stream>>>(in,
                                         xd, xd + XD_PLANE, xd + 2 * XD_PLANE, xd + 3 * XD_PLANE);

    for (int t = 0; t < TT; ++t) {
        const int8_t* srd = (t & 1) ? spk1 : spk0;
        int8_t*       swr = (t & 1) ? spk0 : spk1;
        step_kernel<<<NBLK, 256, 0, stream>>>(whhd, wihd, xd, srd, swr, h_mem, alpha,
                                              b_ih, b_hh, W_ho, b_ho,
                                              o_mem, o_spk, o_sum, t);
    }
    // t=63's spikes are in spk0 (t=63 odd -> swr = spk0)
    final_kernel<<<NBLK, 256, 0, stream>>>(spk0, W_ho, b_ho, alpha, o_mem, o_spk, o_sum,
                                           (float*)d_out);
}

// Round 12
// 1242.901 us; speedup vs baseline: 2.5141x; 1.2402x over previous
//
#include <hip/hip_runtime.h>
#include <stdint.h>

typedef __attribute__((ext_vector_type(4))) int i32x4;

static constexpr int BB = 256, TT = 64, NIN = 700, NKP = 768, HH = 2048, OO = 20;
static constexpr float THRESH_V = 0.3f;
static constexpr int NBLK = 256;                 // 4 m-tiles (M64) x 64 n-tiles (N32); block g owns batch g's o-dots
static constexpr int NREC = 16;                  // rec K-chunks (128B each -> K=2048)
static constexpr int XNIT = 11;                  // x K-chunks (64B each -> K=704 >= 700; rest zero-pad, exact skip)
static constexpr int NIT  = NREC + XNIT;         // 27

// ---------------- ws layout (bytes) ---- validated round-5 layout ----------------
static constexpr size_t OFF_HMEM  = 0;           // 256*2048*4
static constexpr size_t OFF_SPK0  = 2097152;     // 256*2048*1 (i8)
static constexpr size_t OFF_OMEM  = 2621440;
static constexpr size_t OFF_OSPK  = 2641920;
static constexpr size_t OFF_OSUM  = 2662400;
static constexpr size_t ZERO_END  = 2682880;     // memset [0, ZERO_END) every launch
static constexpr size_t OFF_SPK1  = 2682880;
static constexpr size_t OFF_ALPHA = 3207168;
static constexpr size_t OFF_WHHD  = 3207424;     // 4 planes x 2048*2048 i8
static constexpr size_t WHH_PLANE = 4194304;
static constexpr size_t OFF_WIHD  = 19984640;    // 4 planes x 2048*768 i8
static constexpr size_t WIH_PLANE = 1572864;
static constexpr size_t OFF_XD    = 26276096;    // 4 planes x 64*256*768 i8
static constexpr size_t XD_PLANE  = 12582912;
static constexpr size_t WS_NEED   = 76607744;    // known-OK since round 4

// ---------------- sync primitives ----------------
// 3 loads/wave/chunk, depth-3 prefetch: wait leaves 2 chunks (6 loads) in flight.
#define WAIT_VM6()  asm volatile("s_waitcnt vmcnt(6)" ::: "memory")
#define WAIT_VM3()  asm volatile("s_waitcnt vmcnt(3)" ::: "memory")
#define WAIT_VM0()  asm volatile("s_waitcnt vmcnt(0)" ::: "memory")
#define SCHED0()    __builtin_amdgcn_sched_barrier(0)

// ---------------- digit helpers (identical to validated round 5) ----------------
__device__ __forceinline__ void wdig(float w, double scale, signed char d[4]) {
    int q = (int)rint((double)w * scale);
    int t0 = (int)(signed char)(q & 0xFF); q = (q - t0) >> 8;
    int t1 = (int)(signed char)(q & 0xFF); q = (q - t1) >> 8;
    int t2 = (int)(signed char)(q & 0xFF); q = (q - t2) >> 8;
    d[0] = (signed char)t0; d[1] = (signed char)t1;
    d[2] = (signed char)t2; d[3] = (signed char)q;
}

// ---------------- LDS fragment reads (validated) ----------------
__device__ __forceinline__ i32x4 ld_rec(const uint8_t* base, int row, int sl) {
    return *reinterpret_cast<const i32x4*>(base + row * 128 + ((sl ^ (row & 7)) << 4));
}
__device__ __forceinline__ i32x4 ld_x(const uint8_t* base, int row, int s) {
    int phys = (s + (row >> 1)) & 3;
    return *reinterpret_cast<const i32x4*>(base + row * 64 + (phys << 4));
}

__device__ __forceinline__ void gload(const uint8_t* src, uint8_t* dst) {
    __builtin_amdgcn_global_load_lds((const __attribute__((address_space(1))) void*)src,
                                     (__attribute__((address_space(3))) void*)dst, 16, 0, 0);
}

// ---------------- stage one 24KB chunk: 24 x 1KB units, 3 per wave (8 waves) ----------------
// Same byte layout + pre-swizzled sources as the validated 4-wave version; only the
// unit->wave mapping changed (write order is irrelevant: barrier precedes reads).
__device__ __forceinline__ void stage_rec(uint8_t* buf, const int8_t* spk, const int8_t* whhd,
                                          int m0, int n0, int k0B, int wid, int lane) {
#pragma unroll
    for (int i = 0; i < 3; ++i) {
        int u = wid * 3 + i;                         // 0..23 (uniform per wave)
        if (u < 8) {                                 // A: spk 64 rows x 128B @0
            int row = u * 8 + (lane >> 3);
            int s   = (lane & 7) ^ (row & 7);
            gload((const uint8_t*)spk + (size_t)(m0 + row) * HH + k0B + (s << 4),
                  buf + u * 1024);
        } else {                                     // B: whh 4 planes x (32 x 128B) @8192
            int v = u - 8, p = v >> 2, sub = v & 3;
            int row = sub * 8 + (lane >> 3);
            int s   = (lane & 7) ^ (row & 7);
            gload((const uint8_t*)whhd + (size_t)p * WHH_PLANE +
                  (size_t)(n0 + row) * HH + k0B + (s << 4),
                  buf + 8192 + p * 4096 + sub * 1024);
        }
    }
}
__device__ __forceinline__ void stage_x(uint8_t* buf, const int8_t* xd_t, const int8_t* wihd,
                                        int m0, int n0, int k0B, int wid, int lane) {
#pragma unroll
    for (int i = 0; i < 3; ++i) {
        int u = wid * 3 + i;                         // 0..23
        if (u < 16) {                                // A: xd 4 planes x (64 x 64B) @0
            int p = u >> 2, sub = u & 3;
            int row = sub * 16 + (lane >> 2);
            int s   = ((lane & 3) - (row >> 1)) & 3;
            gload((const uint8_t*)xd_t + (size_t)p * XD_PLANE +
                  (size_t)(m0 + row) * NKP + k0B + (s << 4),
                  buf + p * 4096 + sub * 1024);
        } else {                                     // B: wih 4 planes x (32 x 64B) @16384
            int v = u - 16, p = v >> 1, sub = v & 1;
            int row = sub * 16 + (lane >> 2);
            int s   = ((lane & 3) - (row >> 1)) & 3;
            gload((const uint8_t*)wihd + (size_t)p * WIH_PLANE +
                  (size_t)(n0 + row) * NKP + k0B + (s << 4),
                  buf + 16384 + p * 2048 + sub * 1024);
        }
    }
}

// ---------------- MFMA phases (8 waves: each wave owns a 16m x 16n frag) ----------------
__device__ __forceinline__ void mfma_rec(const uint8_t* buf, int mw, int nw, int fr, int hi4,
                                         i32x4 aR[4]) {
#pragma unroll
    for (int ks = 0; ks < 2; ++ks) {
        int sl = ks * 4 + hi4;
        i32x4 a = ld_rec(buf, mw * 16 + fr, sl);
#pragma unroll
        for (int p = 0; p < 4; ++p) {
            i32x4 b = ld_rec(buf + 8192 + p * 4096, nw * 16 + fr, sl);
            aR[p] = __builtin_amdgcn_mfma_i32_16x16x64_i8(a, b, aR[p], 0, 0, 0);
        }
    }
}
__device__ __forceinline__ void mfma_x(const uint8_t* buf, int mw, int nw, int fr, int hi4,
                                       i32x4 aX[5]) {
    i32x4 fa[4], fb[4];
#pragma unroll
    for (int p = 0; p < 4; ++p) {
        fa[p] = ld_x(buf + p * 4096,         mw * 16 + fr, hi4);
        fb[p] = ld_x(buf + 16384 + p * 2048, nw * 16 + fr, hi4);
    }
#pragma unroll
    for (int a = 0; a < 4; ++a)
#pragma unroll
        for (int b = 0; b < 4; ++b) {
            if (a + b < 2) continue;                 // dropped terms ~2e-9 rms (validated)
            const int c = a + b - 2;
            aX[c] = __builtin_amdgcn_mfma_i32_16x16x64_i8(fa[a], fb[b], aX[c], 0, 0, 0);
        }
}

// ---------------- conversion kernels (unchanged, validated) ----------------
__global__ __launch_bounds__(256) void conv_whh_i8(const float* __restrict__ W,
                                                   int8_t* __restrict__ p0, int8_t* __restrict__ p1,
                                                   int8_t* __restrict__ p2, int8_t* __restrict__ p3,
                                                   const float* __restrict__ tau_h,
                                                   const float* __restrict__ tau_o,
                                                   float* __restrict__ alpha) {
    int idx = blockIdx.x * 256 + threadIdx.x;
    if (idx == 0) {
        float qh = __fdiv_rn(-1.0f, tau_h[0]);
        float qo = __fdiv_rn(-1.0f, tau_o[0]);
        alpha[0] = (float)exp((double)qh);
        alpha[1] = (float)exp((double)qo);
    }
    float4 v = reinterpret_cast<const float4*>(W)[idx];
    signed char dx[4], dy[4], dz[4], dw[4];
    const double SC = 1073741824.0;  // 2^30
    wdig(v.x, SC, dx); wdig(v.y, SC, dy); wdig(v.z, SC, dz); wdig(v.w, SC, dw);
    reinterpret_cast<char4*>(p0)[idx] = make_char4(dx[0], dy[0], dz[0], dw[0]);
    reinterpret_cast<char4*>(p1)[idx] = make_char4(dx[1], dy[1], dz[1], dw[1]);
    reinterpret_cast<char4*>(p2)[idx] = make_char4(dx[2], dy[2], dz[2], dw[2]);
    reinterpret_cast<char4*>(p3)[idx] = make_char4(dx[3], dy[3], dz[3], dw[3]);
}

__global__ __launch_bounds__(256) void conv_wih_i8(const float* __restrict__ W,
                                                   int8_t* __restrict__ p0, int8_t* __restrict__ p1,
                                                   int8_t* __restrict__ p2, int8_t* __restrict__ p3) {
    int row = blockIdx.x;
    for (int i = threadIdx.x; i < NKP; i += 256) {
        float v = (i < NIN) ? W[(size_t)row * NIN + i] : 0.f;
        signed char d[4];
        wdig(v, 1073741824.0, d);        // 2^30
        size_t o = (size_t)row * NKP + i;
        p0[o] = d[0]; p1[o] = d[1]; p2[o] = d[2]; p3[o] = d[3];
    }
}

__global__ __launch_bounds__(256) void conv_x_i8(const float* __restrict__ in,
                                                 int8_t* __restrict__ p0, int8_t* __restrict__ p1,
                                                 int8_t* __restrict__ p2, int8_t* __restrict__ p3) {
    int blk = blockIdx.x;
    int t = blk >> 8, b = blk & 255;
    const float* src = in + ((size_t)b * TT + t) * NIN;   // input [B,T,N]
    size_t dst = ((size_t)t * BB + b) * NKP;              // digits [T,B,NKP]
    for (int i = threadIdx.x; i < NKP; i += 256) {
        float v = (i < NIN) ? src[i] : 0.f;
        signed char d[4];
        wdig(v, 16777216.0, d);          // 2^24
        p0[dst + i] = d[0]; p1[dst + i] = d[1]; p2[dst + i] = d[2]; p3[dst + i] = d[3];
    }
}

// ---------------- output-LIF: block g owns batch g; 8 waves cover o = wid + 8p ----------------
// Per-output math identical to validated round-8 o_dot_wave (lane k-slice sum + f64 butterfly).
__device__ __forceinline__ void odot_block(int g, int wid, int lane, const int8_t* __restrict__ spk,
                                           const float* __restrict__ W_ho,
                                           const float* __restrict__ b_ho,
                                           float a_o, float* __restrict__ o_mem,
                                           float* __restrict__ o_spk, float* __restrict__ o_sum,
                                           float* __restrict__ out /*nullptr unless final*/) {
    const int8_t* srow = spk + (size_t)g * HH + lane * 32;
    int4 s0 = *reinterpret_cast<const int4*>(srow);
    int4 s1 = *reinterpret_cast<const int4*>(srow + 16);
    int sw[8] = {s0.x, s0.y, s0.z, s0.w, s1.x, s1.y, s1.z, s1.w};
#pragma unroll 1
    for (int p = 0; p < 3; ++p) {
        int o = wid + 8 * p;
        if (o >= OO) break;
        const float* wrow = W_ho + (size_t)o * HH + lane * 32;
        double acc = 0.0;
#pragma unroll
        for (int q = 0; q < 8; ++q) {
            float4 w = *reinterpret_cast<const float4*>(wrow + q * 4);
            int sv = sw[q];
            acc += (sv & 0x000000FF) ? (double)w.x : 0.0;
            acc += (sv & 0x0000FF00) ? (double)w.y : 0.0;
            acc += (sv & 0x00FF0000) ? (double)w.z : 0.0;
            acc += (sv & 0xFF000000) ? (double)w.w : 0.0;
        }
#pragma unroll
        for (int off = 32; off >= 1; off >>= 1)
            acc += __shfl_xor(acc, off, 64);
        if (lane == 0) {
            float dot = (float)acc;
            size_t oo = (size_t)g * OO + o;
            float om = o_mem[oo], osp = o_spk[oo];
            float v = __fadd_rn(__fadd_rn(__fmul_rn(__fmul_rn(om, a_o), 1.f - osp), dot), b_ho[o]);
            float sn = (v > THRESH_V) ? 1.f : 0.f;
            o_mem[oo] = v;
            o_spk[oo] = sn;
            float s = __fadd_rn(o_sum[oo], sn);
            o_sum[oo] = s;
            if (out) out[oo] = __fmul_rn(s, 1.f / 64.f);
        }
    }
}

// ---------------- per-step kernel: 256 blocks x 512 threads (8 waves = 2/SIMD) ----------------
__global__ __launch_bounds__(512) void step_kernel(
    const int8_t* __restrict__ whhd, const int8_t* __restrict__ wihd,
    const int8_t* __restrict__ xd,
    const int8_t* __restrict__ spk_rd, int8_t* __restrict__ spk_wr,
    float* __restrict__ h_mem, const float* __restrict__ alpha,
    const float* __restrict__ b_ih, const float* __restrict__ b_hh,
    const float* __restrict__ W_ho, const float* __restrict__ b_ho,
    float* __restrict__ o_mem, float* __restrict__ o_spk, float* __restrict__ o_sum,
    int t) {
    // four statically-named 24KB buffers -> depth-3 prefetch, counted vmcnt survives
    __shared__ __align__(16) uint8_t L0[24576];
    __shared__ __align__(16) uint8_t L1[24576];
    __shared__ __align__(16) uint8_t L2[24576];
    __shared__ __align__(16) uint8_t L3[24576];

    int g   = blockIdx.x;                // 0..255
    int tid = threadIdx.x;
    int lane = tid & 63, wid = tid >> 6; // 8 waves
    int m0 = (g >> 6) * 64;              // 4 m-tiles of 64 batches
    int n0 = (g & 63) * 32;              // 64 n-tiles; same-n blocks 64 apart -> same XCD
    int mw = wid >> 1, nw = wid & 1;     // wave covers 16m x 16n of the 64x32 tile
    int fr = lane & 15, hi4 = lane >> 4;

    const int8_t* xd_t = xd + (size_t)t * BB * NKP;

    i32x4 aR[4] = {};                    // rec digit accumulators [plane]
    i32x4 aX[5] = {};                    // x digit-pair accumulators [a+b-2]

    // prologue: 3 chunks in flight (9 loads/wave)
    stage_rec(L0, spk_rd, whhd, m0, n0, 0,   wid, lane);
    stage_rec(L1, spk_rd, whhd, m0, n0, 128, wid, lane);
    stage_rec(L2, spk_rd, whhd, m0, n0, 256, wid, lane);

#pragma unroll
    for (int h = 0; h < NIT; ++h) {
        if (h < NIT - 2) { WAIT_VM6(); }
        else if (h == NIT - 2) { WAIT_VM3(); }
        else { WAIT_VM0(); }             // chunk h's 3 loads complete
        SCHED0();
        __builtin_amdgcn_s_barrier();    // all waves have chunk h; mfma(h-1) reads done
        if (h + 3 < NIT) {               // stage chunk h+3 into L[(h+3)&3]
            uint8_t* nb = ((h + 3) & 3) == 0 ? L0 : ((h + 3) & 3) == 1 ? L1
                        : ((h + 3) & 3) == 2 ? L2 : L3;
            int c = h + 3;
            if (c < NREC) stage_rec(nb, spk_rd, whhd, m0, n0, c * 128, wid, lane);
            else          stage_x(nb, xd_t, wihd, m0, n0, (c - NREC) * 64, wid, lane);
        }
        const uint8_t* cb = (h & 3) == 0 ? L0 : (h & 3) == 1 ? L1
                          : (h & 3) == 2 ? L2 : L3;
        __builtin_amdgcn_s_setprio(1);
        if (h < NREC) mfma_rec(cb, mw, nw, fr, hi4, aR);
        else          mfma_x(cb, mw, nw, fr, hi4, aX);
        __builtin_amdgcn_s_setprio(0);
    }

    // ---- epilogue: LIF update, np's exact op order (validated round 5) ----
    float a_h = alpha[0];
    int j  = n0 + nw * 16 + fr;
    int rq = hi4 * 4;
#pragma unroll
    for (int rr = 0; rr < 4; ++rr) {
        int b = m0 + mw * 16 + rq + rr;
        size_t off = (size_t)b * HH + j;
        float recf = (float)((double)aR[3][rr] * 0x1p-6
                           + (double)aR[2][rr] * 0x1p-14
                           + (double)aR[1][rr] * 0x1p-22
                           + (double)aR[0][rr] * 0x1p-30);
        double xp64 = (double)aX[4][rr] * 0x1p-6
                    + (double)aX[3][rr] * 0x1p-14
                    + (double)aX[2][rr] * 0x1p-22
                    + (double)aX[1][rr] * 0x1p-30
                    + (double)aX[0][rr] * 0x1p-38;
        float xpf = (float)xp64;
        float xpb = __fadd_rn(xpf, b_ih[j]);
        float hv  = h_mem[off];
        float keep = spk_rd[off] ? 0.f : 1.f;
        float v = __fadd_rn(__fmul_rn(__fmul_rn(hv, a_h), keep), xpb);
        v = __fadd_rn(v, recf);
        v = __fadd_rn(v, b_hh[j]);
        h_mem[off] = v;
        spk_wr[off] = (v > THRESH_V) ? (int8_t)1 : (int8_t)0;
    }

    // ---- inline output-LIF for step t-1 (spikes = spk_rd); 8 waves, 2-3 outputs each ----
    if (t > 0)
        odot_block(g, wid, lane, spk_rd, W_ho, b_ho, alpha[1], o_mem, o_spk, o_sum, nullptr);
}

__global__ __launch_bounds__(512) void final_kernel(const int8_t* __restrict__ spk,
                                                    const float* __restrict__ W_ho,
                                                    const float* __restrict__ b_ho,
                                                    const float* __restrict__ alpha,
                                                    float* __restrict__ o_mem,
                                                    float* __restrict__ o_spk,
                                                    float* __restrict__ o_sum,
                                                    float* __restrict__ out) {
    int lane = threadIdx.x & 63, wid = threadIdx.x >> 6;
    odot_block(blockIdx.x, wid, lane, spk, W_ho, b_ho, alpha[1], o_mem, o_spk, o_sum, out);
}

// ---------------- host ----------------
extern "C" void kernel_launch(void* const* d_in, const int* in_sizes, int n_in,
                              void* d_out, int out_size, void* d_ws, size_t ws_size,
                              hipStream_t stream) {
    const float* in    = (const float*)d_in[0];
    const float* W_ih  = (const float*)d_in[1];
    const float* b_ih  = (const float*)d_in[2];
    const float* W_hh  = (const float*)d_in[3];
    const float* b_hh  = (const float*)d_in[4];
    const float* W_ho  = (const float*)d_in[5];
    const float* b_ho  = (const float*)d_in[6];
    const float* tau_h = (const float*)d_in[7];
    const float* tau_o = (const float*)d_in[8];

    uint8_t* ws = (uint8_t*)d_ws;
    float*  h_mem = (float*)(ws + OFF_HMEM);
    int8_t* spk0  = (int8_t*)(ws + OFF_SPK0);
    float*  o_mem = (float*)(ws + OFF_OMEM);
    float*  o_spk = (float*)(ws + OFF_OSPK);
    float*  o_sum = (float*)(ws + OFF_OSUM);
    int8_t* spk1  = (int8_t*)(ws + OFF_SPK1);
    float*  alpha = (float*)(ws + OFF_ALPHA);
    int8_t* whhd  = (int8_t*)(ws + OFF_WHHD);
    int8_t* wihd  = (int8_t*)(ws + OFF_WIHD);
    int8_t* xd    = (int8_t*)(ws + OFF_XD);

    if (ws_size < WS_NEED) return;  // insufficient scratch -> output stays poison (diagnostic)

    hipMemsetAsync(ws, 0, ZERO_END, stream);
    conv_whh_i8<<<4096, 256, 0, stream>>>(W_hh,
                                          whhd, whhd + WHH_PLANE, whhd + 2 * WHH_PLANE, whhd + 3 * WHH_PLANE,
                                          tau_h, tau_o, alpha);
    conv_wih_i8<<<2048, 256, 0, stream>>>(W_ih,
                                          wihd, wihd + WIH_PLANE, wihd + 2 * WIH_PLANE, wihd + 3 * WIH_PLANE);
    conv_x_i8<<<16384, 256, 0, stream>>>(in,
                                         xd, xd + XD_PLANE, xd + 2 * XD_PLANE, xd + 3 * XD_PLANE);

    for (int t = 0; t < TT; ++t) {
        const int8_t* srd = (t & 1) ? spk1 : spk0;
        int8_t*       swr = (t & 1) ? spk0 : spk1;
        step_kernel<<<NBLK, 512, 0, stream>>>(whhd, wihd, xd, srd, swr, h_mem, alpha,
                                              b_ih, b_hh, W_ho, b_ho,
                                              o_mem, o_spk, o_sum, t);
    }
    // t=63's spikes are in spk0 (t=63 odd -> swr = spk0)
    final_kernel<<<NBLK, 512, 0, stream>>>(spk0, W_ho, b_ho, alpha, o_mem, o_spk, o_sum,
                                           (float*)d_out);
}